// Round 1
// baseline (165.351 us; speedup 1.0000x reference)
//
#include <hip/hip_runtime.h>
#include <hip/hip_fp16.h>

#define GSZ 640
#define NIMG 320
#define MS 102400
#define NC 12
#define BETA_F 13.8551004f
#define TWOPI_F 6.2831855f
// fp16 grid scaling: G is ~1e-9..1e-10 in the reference's un-normalized KB
// convention. Scale by 2^24 ONCE in passA; fold 2^-24 into the tap weights.
#define GSC 16777216.0f
#define GSC_INV 5.9604645e-8f

// ---------- Bessel I0 (Abramowitz & Stegun 9.8.1 / 9.8.2, rel err < 2e-7) ----------
__device__ __forceinline__ float i0f(float x) {
    float ax = fabsf(x);
    if (ax < 3.75f) {
        float t = ax * (1.0f / 3.75f);
        t *= t;
        return 1.0f + t * (3.5156229f + t * (3.0899424f + t * (1.2067492f +
                     t * (0.2659732f + t * (0.0360768f + t * 0.0045813f)))));
    } else {
        float t = 3.75f / ax;
        float p = 0.39894228f + t * (0.01328592f + t * (0.00225319f + t * (-0.00157565f +
                  t * (0.00916281f + t * (-0.02057706f + t * (0.02635537f +
                  t * (-0.01647633f + t * 0.00392377f)))))));
        return p * __expf(ax) * rsqrtf(ax);
    }
}

// Kaiser-Bessel kernel, support |u| <= 3 (J=6)
__device__ __forceinline__ float kbval(float u) {
    float mm = fabsf(u) * (1.0f / 3.0f);
    float s = 1.0f - mm * mm;
    s = s > 0.0f ? s : 0.0f;
    float v = i0f(BETA_F * sqrtf(s)) * (1.0f / 6.0f);
    return (mm <= 1.0f) ? v : 0.0f;
}

__device__ __forceinline__ float2 cmul(float2 a, float2 w) {
    return make_float2(a.x * w.x - a.y * w.y, a.x * w.y + a.y * w.x);
}

// Stockham DIF radix-4 stage with LDS twiddle table. 160 butterflies, t < 160.
__device__ __forceinline__ void radix4_stage(const float2* src, float2* dst,
                                             const float2* tw, int t, int s,
                                             int n, int mult) {
    int p = t / s, q = t - p * s;
    int m = n >> 2;
    float2 a0 = src[q + s * p];
    float2 a1 = src[q + s * (p + m)];
    float2 a2 = src[q + s * (p + 2 * m)];
    float2 a3 = src[q + s * (p + 3 * m)];
    float2 e = make_float2(a0.x + a2.x, a0.y + a2.y);
    float2 f = make_float2(a1.x + a3.x, a1.y + a3.y);
    float2 g = make_float2(a0.x - a2.x, a0.y - a2.y);
    float2 h = make_float2(a1.x - a3.x, a1.y - a3.y);
    float2 B0 = make_float2(e.x + f.x, e.y + f.y);
    float2 B2 = make_float2(e.x - f.x, e.y - f.y);
    float2 mih = make_float2(h.y, -h.x);                 // -i*h
    float2 B1 = make_float2(g.x + mih.x, g.y + mih.y);
    float2 B3 = make_float2(g.x - mih.x, g.y - mih.y);
    int pm = p * mult;
    dst[q + s * (4 * p)]     = B0;
    dst[q + s * (4 * p + 1)] = cmul(B1, tw[pm]);
    dst[q + s * (4 * p + 2)] = cmul(B2, tw[2 * pm]);
    dst[q + s * (4 * p + 3)] = cmul(B3, tw[3 * pm]);
}

// ---------- 640-point FFT: radix-5, 3x radix-4 (LDS), final radix-2 in regs ----------
// tw = 640-entry LDS twiddle table, built by caller BEFORE the first barrier here.
// NOTE (iteration safety): after the final in-function barrier, thread t reads only
// bA[t], bA[t+320] — the exact two slots the SAME thread rewrites as its next-call
// input; bB is next written only after the next call's entry barrier. So fft640 can
// be called in a loop with no extra barriers between calls.
__device__ void fft640(float2* bA, float2* bB, const float2* tw, int t,
                       float2* olo, float2* ohi) {
    __syncthreads();   // bA + tw ready
    if (t < 128) {
        float2 aj[5];
        #pragma unroll
        for (int j = 0; j < 5; ++j) aj[j] = bA[t + 128 * j];
        const float wr[5] = {1.0f, 0.30901699f, -0.80901699f, -0.80901699f, 0.30901699f};
        const float wi[5] = {0.0f, -0.95105652f, -0.58778525f, 0.58778525f, 0.95105652f};
        #pragma unroll
        for (int r = 0; r < 5; ++r) {
            float br = aj[0].x, bi = aj[0].y;
            #pragma unroll
            for (int j = 1; j < 5; ++j) {
                int k = (j * r) % 5;
                br += aj[j].x * wr[k] - aj[j].y * wi[k];
                bi += aj[j].x * wi[k] + aj[j].y * wr[k];
            }
            bB[5 * t + r] = cmul(make_float2(br, bi), tw[t * r]);  // idx <= 508
        }
    }
    __syncthreads();
    if (t < 160) radix4_stage(bB, bA, tw, t, 5, 128, 5);
    __syncthreads();
    if (t < 160) radix4_stage(bA, bB, tw, t, 20, 32, 20);
    __syncthreads();
    if (t < 160) radix4_stage(bB, bA, tw, t, 80, 8, 80);
    __syncthreads();
    float2 a = bA[t], b = bA[t + 320];
    *olo = make_float2(a.x + b.x, a.y + b.y);
    *ohi = make_float2(a.x - b.x, a.y - b.y);
}

// ---------- apodization table: 1 block, 320 threads ----------
__global__ __launch_bounds__(320)
void apod_kernel(float* __restrict__ apod) {
    int n = threadIdx.x;
    float s = 0.0f;
    #pragma unroll
    for (int j = -3; j <= 3; ++j)
        s += kbval((float)j) * __cosf((TWOPI_F * (float)j * ((float)n - 160.0f)) / 640.0f);
    apod[n] = 1.0f / s;
}

// ---------- pass A: row FFT, 2 rows/block; writes R16[c][ri][q] fp16 scaled ----------
__global__ __launch_bounds__(640)
void passA_kernel(const float* __restrict__ img_r, const float* __restrict__ img_i,
                  const float* __restrict__ sm_r, const float* __restrict__ sm_i,
                  const float* __restrict__ apod, unsigned int* __restrict__ R16) {
    __shared__ float2 bA[2][GSZ], bB[2][GSZ], tw[GSZ];
    {
        float sn, cs;
        __sincosf((-TWOPI_F / 640.0f) * (float)threadIdx.x, &sn, &cs);
        tw[threadIdx.x] = make_float2(cs, sn);
    }
    int e = threadIdx.x >= 320;
    int t = threadIdx.x - 320 * e;
    int ri = 2 * blockIdx.x + e, c = blockIdx.y;
    int h = (ri < 160) ? ri + 160 : ri - 160;
    int w = (t < 160) ? t + 160 : t - 160;
    float scale = apod[h] * apod[w] * (GSC / 640.0f);
    float xr = img_r[h * NIMG + w];
    float xi = img_i[h * NIMG + w];
    float sr = sm_r[(c * NIMG + h) * NIMG + w];
    float si = sm_i[(c * NIMG + h) * NIMG + w];
    float vr = (xr * sr - xi * si) * scale;
    float vi = (xr * si + xi * sr) * scale;
    int vnz = (t < 160) ? t : t + 320;   // ifftshifted column position
    int vz  = (t < 160) ? t + 320 : t;
    bA[e][vnz] = make_float2(vr, vi);
    bA[e][vz]  = make_float2(0.0f, 0.0f);
    float2 lo, hi;
    fft640(bA[e], bB[e], tw, t, &lo, &hi);
    __half2 hlo = __float22half2_rn(lo);
    __half2 hhi = __float22half2_rn(hi);
    unsigned int* out = R16 + (c * 320 + ri) * GSZ;
    out[t]       = *(const unsigned int*)&hlo;
    out[t + 320] = *(const unsigned int*)&hhi;
}

// ---------- pass B1G: column FFT for ALL 12 coils of one q, fused transpose ----------
// 640 threads run 2 coils per iteration (e = coil parity), 6 iterations.
// Per-coil results stash into Gs[c][u] (write: lane-consecutive u, conflict-free),
// then one coalesced uint4 shuffle-write emits G[q][u][c] directly.
// Deletes old passB2's F round-trip (19.7MB write + 19.7MB read).
__global__ __launch_bounds__(640)
void passB1G_kernel(const unsigned int* __restrict__ R16, unsigned int* __restrict__ G) {
    __shared__ float2 bA[2][GSZ], bB[2][GSZ], tw[GSZ];
    __shared__ unsigned int Gs[NC][GSZ + 1];
    {
        float sn, cs;
        __sincosf((-TWOPI_F / 640.0f) * (float)threadIdx.x, &sn, &cs);
        tw[threadIdx.x] = make_float2(cs, sn);
    }
    // XCD-bijective swizzle: 640 = 8*80, consecutive q share R16 cache lines,
    // keep each 80-q chunk on one XCD's L2.
    int q = (blockIdx.x % 8) * 80 + blockIdx.x / 8;
    int e = threadIdx.x >= 320;
    int t = threadIdx.x - 320 * e;
    int rnz = (t < 160) ? t : t + 320;
    int rz  = (t < 160) ? t + 320 : t;
    #pragma unroll 1
    for (int cp = 0; cp < 6; ++cp) {
        int c = 2 * cp + e;
        unsigned int raw = R16[(c * 320 + t) * GSZ + q];   // strided gather, L2/L3 hit
        bA[e][rnz] = __half22float2(*(const __half2*)&raw);
        bA[e][rz]  = make_float2(0.0f, 0.0f);
        float2 lo, hi;
        fft640(bA[e], bB[e], tw, t, &lo, &hi);
        __half2 hlo = __float22half2_rn(lo);
        __half2 hhi = __float22half2_rn(hi);
        Gs[c][t]       = *(const unsigned int*)&hlo;
        Gs[c][t + 320] = *(const unsigned int*)&hhi;
    }
    __syncthreads();   // all 12 coils stashed
    uint4* out4 = (uint4*)(G + (size_t)q * (GSZ * NC));    // 1920 uint4 per q
    #pragma unroll
    for (int j = 0; j < 3; ++j) {
        int k = threadIdx.x + 640 * j;
        int w = 4 * k;                                     // uint index = u*12 + c
        uint4 v;
        v.x = Gs[(w)     % 12][(w)     / 12];
        v.y = Gs[(w + 1) % 12][(w + 1) / 12];
        v.z = Gs[(w + 2) % 12][(w + 2) / 12];
        v.w = Gs[(w + 3) % 12][(w + 3) / 12];
        out4[k] = v;
    }
}

// ---------- tap computation (inline in interp; ~400 VALU instrs/lane, ~1.5us chip) ----------
__device__ __forceinline__ void taps(float om, float* w, int* idx) {
    float t = fmodf((om * 640.0f) / TWOPI_F, 640.0f);
    if (t < 0.0f) t += 640.0f;
    float base = floorf(t);
    float frac = t - base;
    int ib = (int)base;
    #pragma unroll
    for (int j = 0; j < 6; ++j) {
        w[j] = kbval(frac + (float)(2 - j));  // u = t - (base + j - 2)
        int k = ib + j - 2;
        if (k < 0) k += GSZ;
        if (k >= GSZ) k -= GSZ;
        idx[j] = k;
    }
}

// ---------- interpolation: 3 lanes/sample, 4 coils/lane via float4 gathers ----------
// Taps recomputed per lane (replaces the 8.2MB TapRec table that interp used to
// read 3x over = 24.6MB; recompute is ~free on the VALU).
__global__ __launch_bounds__(256)
void interp_kernel(const float* __restrict__ kt, const float4* __restrict__ G4,
                   float2* __restrict__ out) {
    int tid = blockIdx.x * 256 + threadIdx.x;   // 307200 = 1200*256 exactly
    int m = tid / 3;
    int p = tid - 3 * m;                        // coil quad index 0..2
    float w1[6], w2[6];
    int iu[6], iv[6];
    taps(kt[m], w1, iu);
    taps(kt[MS + m], w2, iv);
    float ar[4] = {0.f, 0.f, 0.f, 0.f}, ai[4] = {0.f, 0.f, 0.f, 0.f};
    #pragma unroll
    for (int j2 = 0; j2 < 6; ++j2) {
        int rb = iv[j2] * (GSZ * 3) + p;        // float4 units: 3 per (v,u)
        float b2 = w2[j2] * GSC_INV;
        #pragma unroll
        for (int j1 = 0; j1 < 6; ++j1) {
            float4 gq = G4[rb + iu[j1] * 3];
            const __half2* h = (const __half2*)&gq;   // 4 x (re,im)
            float ww = b2 * w1[j1];
            #pragma unroll
            for (int k = 0; k < 4; ++k) {
                float2 f = __half22float2(h[k]);
                ar[k] = fmaf(ww, f.x, ar[k]);
                ai[k] = fmaf(ww, f.y, ai[k]);
            }
        }
    }
    #pragma unroll
    for (int k = 0; k < 4; ++k)
        out[(4 * p + k) * MS + m] = make_float2(ar[k], ai[k]);
}

extern "C" void kernel_launch(void* const* d_in, const int* in_sizes, int n_in,
                              void* d_out, int out_size, void* d_ws, size_t ws_size,
                              hipStream_t stream) {
    const float* img_r = (const float*)d_in[0];
    const float* img_i = (const float*)d_in[1];
    const float* sm_r  = (const float*)d_in[2];
    const float* sm_i  = (const float*)d_in[3];
    const float* kt    = (const float*)d_in[4];

    // ws layout (~29.5MB): [R16 9.83M][G 19.66M][apod 1.3K]
    char* base = (char*)d_ws;
    unsigned int* R16 = (unsigned int*)base;                    // 12*320*640*4
    unsigned int* G   = (unsigned int*)(base + 9830400);        // 640*640*12*4
    float* apod       = (float*)(base + 29491200);              // 320 floats

    apod_kernel<<<1, 320, 0, stream>>>(apod);
    passA_kernel<<<dim3(160, NC), 640, 0, stream>>>(img_r, img_i, sm_r, sm_i, apod, R16);
    passB1G_kernel<<<GSZ, 640, 0, stream>>>(R16, G);
    interp_kernel<<<1200, 256, 0, stream>>>(kt, (const float4*)G, (float2*)d_out);
}